// Round 8
// baseline (216.840 us; speedup 1.0000x reference)
//
#include <hip/hip_runtime.h>
#include <stdint.h>

#define B_SZ 32
#define T_SZ 300
#define F_IN 3072
#define F_HID 410
#define F_OUT 10
#define M_SZ (B_SZ * T_SZ)              // 9600
#define N_PAD 448                       // a1 row stride = gemm1 N (7 x 64)
#define NCHUNK 10
#define CLEN 30
#define NKB (F_IN / 256)                // 12 K-blocks of 256
#define MT_CNT (M_SZ / 64)              // 150 m-tiles
#define W1_BLOCKS 672                   // 448*3072/8/256
#define RNG_BLOCKS 14400                // 921600*4/256 (4 threads/word, 8 bits each)

// f32(exp(f32(-0.1))) — PSP decay, matches XLA's correctly-rounded exp
#define DECAY 0.90483741803595957f
#define THETA 10.0f
#define KS2 (0x1BD11BDAu ^ 42u)

typedef __attribute__((ext_vector_type(8))) int i32x8;
typedef __attribute__((ext_vector_type(16))) float f32x16;

// FORCED single-instruction rotate-left, in-place. v_alignbit_b32 x,x,x,(32-r)
// = rotl(r). (R3: prep is at the sustainable VALU issue floor.)
#define TF_R(r) { x0 += x1; \
  asm("v_alignbit_b32 %0, %0, %0, %1" : "+v"(x1) : "n"(32 - (r))); \
  x1 ^= x0; }

// JAX partitionable threefry2x32, key=(0,42), ctr=(0, x1i-42). x0 key-add is 0
// (elided); x1 key-add folded into caller's x1i = base + 42 + jj. Returns o0^o1.
__device__ __forceinline__ uint32_t tf_bits(uint32_t x1i) {
  uint32_t x0 = 0u, x1 = x1i;
  TF_R(13) TF_R(15) TF_R(26) TF_R(6)
  x0 += 42u; x1 += KS2 + 1u;
  TF_R(17) TF_R(29) TF_R(16) TF_R(24)
  x0 += KS2; x1 += 2u;
  TF_R(13) TF_R(15) TF_R(26) TF_R(6)
  x1 += 42u + 3u;
  TF_R(17) TF_R(29) TF_R(16) TF_R(24)
  x0 += 42u; x1 += KS2 + 4u;
  TF_R(13) TF_R(15) TF_R(26) TF_R(6)
  x0 += KS2; x1 += 5u;
  return x0 ^ x1;
}

// async global->LDS, 16 B per lane; LDS dest = wave-uniform base + lane*16
__device__ __forceinline__ void gld16(const void* g, void* l) {
  __builtin_amdgcn_global_load_lds(
      (const __attribute__((address_space(1))) uint32_t*)g,
      (__attribute__((address_space(3))) uint32_t*)l, 16, 0, 0);
}

// Merged prep (R4-verified).
// Blocks [0, 672): W1 fp32 -> e4m3, PRE-SWIZZLED into the gemm1 LDS image
//   (rows >= 410 zeroed) so global_load_lds DMA yields conflict-free tiles.
// Blocks [672, 672+14400): partitionable threefry rate-encode, 4 threads per
//   32-bit word. Integer thresholds: u < p <=> (bits>>9) < ceil(p*2^23).
__global__ __launch_bounds__(256) void prep(const float* __restrict__ inp,
                                            const float* __restrict__ W1,
                                            uint8_t* __restrict__ W1s,
                                            uint32_t* __restrict__ sbitsT) {
  if (blockIdx.x < W1_BLOCKS) {
    int idx = blockIdx.x * 256 + threadIdx.x;
    int g = idx * 8;
    int n = g / F_IN;
    int k = g - n * F_IN;
    uint32_t d0 = 0u, d1 = 0u;
    if (n < F_HID) {
      const float* s = W1 + (size_t)n * F_IN + k;
      float4 v0 = ((const float4*)s)[0];
      float4 v1 = ((const float4*)s)[1];
      int t0 = __builtin_amdgcn_cvt_pk_fp8_f32(v0.x, v0.y, 0, false);
      t0 = __builtin_amdgcn_cvt_pk_fp8_f32(v0.z, v0.w, t0, true);
      int t1 = __builtin_amdgcn_cvt_pk_fp8_f32(v1.x, v1.y, 0, false);
      t1 = __builtin_amdgcn_cvt_pk_fp8_f32(v1.z, v1.w, t1, true);
      d0 = (uint32_t)t0; d1 = (uint32_t)t1;
    }
    int nt = n >> 6, r = n & 63;
    int kb = k >> 8, c = (k >> 4) & 15, half = (k >> 3) & 1;
    size_t dst = ((((size_t)nt * NKB + kb) * 64 + r) * 16 + (c ^ (r & 15))) * 16 + half * 8;
    *(uint2*)(W1s + dst) = make_uint2(d0, d1);
  } else {
    uint32_t idx = (blockIdx.x - W1_BLOCKS) * 256u + threadIdx.x;  // [0, 3686400)
    uint32_t q = idx & 3u;          // byte within word
    uint32_t j = idx >> 2;          // word index [0, 921600)
    uint32_t r = j & 63u;
    uint32_t t1 = j >> 6;
    uint32_t wi = t1 & 7u;
    uint32_t t2 = t1 >> 3;          // (mt*12 + kb) in [0, 1800)
    uint32_t kb = t2 % (uint32_t)NKB;
    uint32_t mt = t2 / (uint32_t)NKB;
    uint32_t m = mt * 64u + r;      // GEMM row = b*300 + t
    uint32_t b = m / (uint32_t)T_SZ;
    uint32_t f = (kb * 8u + wi) * 32u + q * 8u;
    const float* p = inp + b * F_IN + f;
    float4 va = ((const float4*)p)[0];
    float4 vb = ((const float4*)p)[1];
    uint32_t T0 = (uint32_t)ceilf(va.x * 8388608.0f);
    uint32_t T1 = (uint32_t)ceilf(va.y * 8388608.0f);
    uint32_t T2 = (uint32_t)ceilf(va.z * 8388608.0f);
    uint32_t T3 = (uint32_t)ceilf(va.w * 8388608.0f);
    uint32_t T4 = (uint32_t)ceilf(vb.x * 8388608.0f);
    uint32_t T5 = (uint32_t)ceilf(vb.y * 8388608.0f);
    uint32_t T6 = (uint32_t)ceilf(vb.z * 8388608.0f);
    uint32_t T7 = (uint32_t)ceilf(vb.w * 8388608.0f);
    uint32_t b42 = m * (uint32_t)F_IN + f + 42u;   // counter base + key lo
    uint32_t w = 0u;
#define GEN(jj, Tn) { uint32_t bits = tf_bits(b42 + (jj)); \
  w |= ((bits >> 9) < (Tn)) ? (1u << (jj)) : 0u; }
    GEN(0, T0) GEN(1, T1) GEN(2, T2) GEN(3, T3)
    GEN(4, T4) GEN(5, T5) GEN(6, T6) GEN(7, T7)
#undef GEN
    ((uint8_t*)sbitsT)[idx] = (uint8_t)w;   // byte q of word j: bits [8q, 8q+8)
  }
}

// a1[m][n] = sum_k spike(m,k)*W1[n][k], MX-fp8 MFMA 32x32x64 (scales=127=2^0).
// BM=64, BN=64, BK=256, grid 150x7=1050, 256 thr = 4 waves (2x2 of 32x32).
// R4-verified 2-phase LDS double-buffer: issue kb+1's DMA, compute kb, one
// barrier per K-block.
__global__ __launch_bounds__(256) void gemm1(const uint32_t* __restrict__ sbitsT,
                                             const uint8_t* __restrict__ W1s,
                                             float* __restrict__ a1) {
  __shared__ uint32_t sAT[2][8 * 64];   // 2x2 KB: [word][row]
  __shared__ uint8_t sB[2][64 * 256];   // 2x16 KB: swizzled LDS image

  const int tid = threadIdx.x;
  const int mtile = blockIdx.x;
  const int nt = blockIdx.y;
  const int m0 = mtile * 64;
  const int n0 = nt * 64;
  const int wv = tid >> 6, lane = tid & 63;
  const int wm = (wv & 1) * 32, wn = (wv >> 1) * 32;
  const int l31 = lane & 31, lh = lane >> 5;

  const uint8_t* gB0 = W1s + (size_t)nt * NKB * 16384;
  const uint8_t* gA0 = (const uint8_t*)sbitsT + (size_t)mtile * NKB * 2048;

  auto STAGE = [&](int buf, int kb) {
    const uint8_t* gB = gB0 + (size_t)kb * 16384;
#pragma unroll
    for (int q = 0; q < 4; ++q)
      gld16(gB + (wv * 4 + q) * 1024 + lane * 16, &sB[buf][(wv * 4 + q) * 1024]);
    if (wv < 2)
      gld16(gA0 + (size_t)kb * 2048 + wv * 1024 + lane * 16,
            (uint8_t*)&sAT[buf][0] + wv * 1024);
  };

  f32x16 acc;
#pragma unroll
  for (int e = 0; e < 16; ++e) acc[e] = 0.0f;

  STAGE(0, 0);
  __syncthreads();             // prologue: only exposed DMA wait
  int cur = 0;
  for (int kb = 0; kb < NKB; ++kb) {
    if (kb + 1 < NKB) STAGE(cur ^ 1, kb + 1);   // in flight during compute
    const uint8_t* sBc = sB[cur];
    const uint32_t* sATc = sAT[cur];
#pragma unroll
    for (int sub = 0; sub < 4; ++sub) {
      // B frag: B[n = wn+l31][k = sub*64 + lh*32 + 0..31]
      int row = wn + l31;
      int cb = sub * 4 + lh * 2;
      uint4 u0 = *(uint4*)&sBc[row * 256 + (((cb + 0) ^ (row & 15)) << 4)];
      uint4 u1 = *(uint4*)&sBc[row * 256 + (((cb + 1) ^ (row & 15)) << 4)];
      i32x8 bfr;
      bfr[0] = u0.x; bfr[1] = u0.y; bfr[2] = u0.z; bfr[3] = u0.w;
      bfr[4] = u1.x; bfr[5] = u1.y; bfr[6] = u1.z; bfr[7] = u1.w;
      // A frag: A[m = wm+l31][same k], expanded bits -> fp8(1.0)=0x38
      uint32_t w = sATc[(sub * 2 + lh) * 64 + wm + l31];
      i32x8 afr;
#pragma unroll
      for (int j = 0; j < 8; ++j) {
        uint32_t n = (w >> (4 * j)) & 15u;
        afr[j] = (int)(((n * 0x204081u) & 0x01010101u) * 0x38u);
      }
      acc = __builtin_amdgcn_mfma_scale_f32_32x32x64_f8f6f4(
          afr, bfr, acc, 0, 0, 0, 127, 0, 127);
    }
    __syncthreads();   // drains this wave's DMA (next buf ready) + LDS reuse
    cur ^= 1;
  }
  // epilogue: C/D 32x32: col = lane&31, row = (reg&3) + 8*(reg>>2) + 4*(lane>>5)
  int col = n0 + wn + l31;
#pragma unroll
  for (int rg = 0; rg < 16; ++rg) {
    int row = m0 + wm + (rg & 3) + 8 * (rg >> 2) + 4 * lh;
    a1[(size_t)row * N_PAD + col] = acc[rg];
  }
}

// R8: the ENTIRE layer-2 path for one batch in one block (block = b, 1024 thr
// = 16 waves). Stages, separated by __syncthreads:
//  1A: per-(chunk,oblk) 30-step scans -> chunk finals in LDS (psp1's exact
//      __fadd_rn(__fmul_rn(DECAY,u),x) chain).
//  1F: chunk-prefix F~ (fscan's exact F = v + d30*F chain), in-place in LDS.
//  1B: RE-scan (identical chain, identical inputs => bit-identical u) +
//      threshold u + dp*F~ >= THETA, one __ballot per (t,oblk) -> spike bits
//      in LDS. Spike bits / a2 never touch global memory.
//   2: gemm2 — one wave per t, verbatim j-loop/fmaf/shuffle-reduce order.
//   3: psp2 verbatim, a2 read from LDS, writes out.
// Replaces 3 dispatches (224+2400+32 blocks) with 1 (32 blocks); removes the
// sb2+a2 global round-trips. Per-block: 537 KB L3-hot a1 reads x2, 16 waves
// of ILP — a few us. LDS 63.9 KB.
__global__ __launch_bounds__(1024) void layer2(const float* __restrict__ a1,
                                               const float* __restrict__ W2,
                                               float* __restrict__ out) {
  __shared__ float sW2[F_OUT * F_HID];     // 16400 B
  __shared__ float finF[NCHUNK][N_PAD];    // 17920 B: finals, then F~ in place
  __shared__ uint32_t sbits[T_SZ][14];     // 16800 B: spike bits [t][oblk*2+half]
  __shared__ float a2s[T_SZ][F_OUT];       // 12000 B
  __shared__ float chf[NCHUNK][F_OUT];     // 400 B
  __shared__ float seed[NCHUNK][F_OUT];    // 400 B
  const int b = blockIdx.x;
  const int tid = threadIdx.x;
  const int w = tid >> 6, lane = tid & 63;

  for (int i = tid; i < F_OUT * F_HID; i += 1024) sW2[i] = W2[i];

  // ---- stage 1A: chunk scans -> finals --------------------------------
  for (int p = w; p < NCHUNK * 7; p += 16) {
    int c = p / 7, ob = p % 7;
    const float* src = a1 + ((size_t)(b * T_SZ + c * CLEN)) * N_PAD + ob * 64 + lane;
    float u = 0.0f;
#pragma unroll
    for (int i = 0; i < CLEN; ++i)
      u = __fadd_rn(__fmul_rn(DECAY, u), src[(size_t)i * N_PAD]);
    finF[c][ob * 64 + lane] = u;
  }
  __syncthreads();

  // ---- stage 1F: chunk-prefix (fscan chain), in place -----------------
  if (tid < N_PAD) {
    float v[NCHUNK];
#pragma unroll
    for (int c = 0; c < NCHUNK; ++c) v[c] = finF[c][tid];
    float d30 = 1.0f;
#pragma unroll
    for (int i = 0; i < CLEN; ++i) d30 *= DECAY;
    float F = 0.0f;
    finF[0][tid] = 0.0f;
#pragma unroll
    for (int c = 1; c < NCHUNK; ++c) {
      F = v[c - 1] + d30 * F;
      finF[c][tid] = F;
    }
  }
  __syncthreads();

  // ---- stage 1B: rescan + threshold + ballot -> sbits -----------------
  for (int p = w; p < NCHUNK * 7; p += 16) {
    int c = p / 7, ob = p % 7;
    const float* src = a1 + ((size_t)(b * T_SZ + c * CLEN)) * N_PAD + ob * 64 + lane;
    float F = finF[c][ob * 64 + lane];
    float u = 0.0f;
    float dp = DECAY;                     // DECAY^(tl+1), ag2's exact sequence
    int m0 = c * CLEN;
#pragma unroll
    for (int i = 0; i < CLEN; ++i) {
      u = __fadd_rn(__fmul_rn(DECAY, u), src[(size_t)i * N_PAD]);
      float uu = (c > 0) ? __fadd_rn(u, __fmul_rn(dp, F)) : u;
      unsigned long long msk = __ballot(uu >= THETA);
      if (lane == 0)
        *(uint2*)&sbits[m0 + i][ob * 2] =
            make_uint2((uint32_t)msk, (uint32_t)(msk >> 32));
      dp *= DECAY;
    }
  }
  __syncthreads();

  // ---- stage 2: gemm2 (one wave per t, verbatim ag2 order) ------------
  for (int m = w; m < T_SZ; m += 16) {
    int lh = lane >> 5;
    float p[F_OUT];
#pragma unroll
    for (int o = 0; o < F_OUT; ++o) p[o] = 0.0f;
#pragma unroll
    for (int j = 0; j < 7; ++j) {
      int hh = lane + j * 64;
      uint32_t wd = sbits[m][j * 2 + lh];
      float s = (float)((wd >> (lane & 31)) & 1u);  // 0 for hh>=F_HID by construction
      int hcl = hh < F_HID ? hh : 0;
#pragma unroll
      for (int o = 0; o < F_OUT; ++o) p[o] = fmaf(s, sW2[o * F_HID + hcl], p[o]);
    }
#pragma unroll
    for (int o = 0; o < F_OUT; ++o)
#pragma unroll
      for (int s2 = 1; s2 < 64; s2 <<= 1) p[o] += __shfl_xor(p[o], s2, 64);
    if (lane < F_OUT) a2s[m][lane] = p[lane];
  }
  __syncthreads();

  // ---- stage 3: psp2 (verbatim) ---------------------------------------
  {
    int o = tid / NCHUNK, c = tid % NCHUNK;
    float v[CLEN];
    float pa[CLEN];
    if (tid < F_OUT * NCHUNK) {
#pragma unroll
      for (int i = 0; i < CLEN; ++i) v[i] = a2s[c * CLEN + i][o];
      float u = 0.0f;
#pragma unroll
      for (int i = 0; i < CLEN; ++i) {
        u = __fadd_rn(__fmul_rn(DECAY, u), v[i]);
        pa[i] = u;
      }
      chf[c][o] = u;
    }
    __syncthreads();
    if (tid < F_OUT) {
      float d30 = 1.0f;
#pragma unroll
      for (int i = 0; i < CLEN; ++i) d30 *= DECAY;
      float F = 0.0f;
      for (int cc = 0; cc < NCHUNK; ++cc) {
        F = chf[cc][tid] + d30 * F;
        seed[cc][tid] = F;
      }
    }
    __syncthreads();
    if (tid < F_OUT * NCHUNK) {
      float F = (c == 0) ? 0.0f : seed[c - 1][o];
      float dp = DECAY;
      float* q = out + (size_t)b * F_OUT * T_SZ + (size_t)o * T_SZ + c * CLEN;
#pragma unroll
      for (int i = 0; i < CLEN; ++i) {
        float u = (c == 0) ? pa[i] : __fadd_rn(pa[i], __fmul_rn(dp, F));
        q[i] = (u >= THETA) ? 1.0f : 0.0f;
        dp *= DECAY;
      }
    }
  }
}

extern "C" void kernel_launch(void* const* d_in, const int* in_sizes, int n_in,
                              void* d_out, int out_size, void* d_ws, size_t ws_size,
                              hipStream_t stream) {
  const float* inp = (const float*)d_in[0];  // [32,3,32,32]
  const float* W1  = (const float*)d_in[1];  // [410,3072]
  const float* W2  = (const float*)d_in[2];  // [10,410]
  float* out = (float*)d_out;                // [32,10,300]
  char* ws = (char*)d_ws;
  // ws: W1s 1376256 | sbitsT 3686400 | a1 17203200
  uint8_t* W1s = (uint8_t*)(ws);
  uint32_t* sbitsT = (uint32_t*)(ws + 1376256);
  float* a1 = (float*)(ws + 1376256 + 3686400);

  prep<<<dim3(W1_BLOCKS + RNG_BLOCKS), dim3(256), 0, stream>>>(inp, W1, W1s, sbitsT);
  gemm1<<<dim3(MT_CNT, N_PAD / 64), dim3(256), 0, stream>>>(sbitsT, W1s, a1);
  layer2<<<dim3(B_SZ), dim3(1024), 0, stream>>>(a1, W2, out);
}